// Round 6
// baseline (283.876 us; speedup 1.0000x reference)
//
#include <hip/hip_runtime.h>
#include <cstdint>

typedef unsigned short u16;
typedef unsigned int u32;
typedef __attribute__((ext_vector_type(8))) __bf16 bf16x8;
typedef __attribute__((ext_vector_type(4))) float f32x4;
typedef __attribute__((ext_vector_type(4))) unsigned short u16x4;

#define AS1 __attribute__((address_space(1)))
#define AS3 __attribute__((address_space(3)))

__device__ __forceinline__ void gload16(const void* g, void* l) {
    __builtin_amdgcn_global_load_lds((AS1 void*)g, (AS3 void*)l, 16, 0, 0);
}

// hardware bf16 convert (v_cvt_pk_bf16_f32), RNE
__device__ __forceinline__ u16 f2bf(float f) {
    return __builtin_bit_cast(u16, (__bf16)f);
}

__device__ __forceinline__ void store_c(u16* p, float v)   { *p = f2bf(v); }
__device__ __forceinline__ void store_c(float* p, float v) { *p = v; }

// ---------------------------------------------------------------------------
// Fused prep: x fp32->bf16 cast + all 4 weight transpose+converts (one launch).
// blocks [0,4096): Wq  [4096,5120): Wk  [5120,6144): Wv  [6144,10240): Wo
// blocks [10240,18432): x cast (4 elems/thread)
// ---------------------------------------------------------------------------
__global__ void prep(const float* __restrict__ x,
                     const float* __restrict__ Wq, const float* __restrict__ Wk,
                     const float* __restrict__ Wv, const float* __restrict__ Wo,
                     u16* __restrict__ xb, u16* __restrict__ Wt)
{
    const int bid = blockIdx.x;
    if (bid >= 10240) {   // x cast
        int tid = threadIdx.y * 32 + threadIdx.x;
        size_t i = ((size_t)(bid - 10240) * 256 + tid) * 4;
        float4 v = *(const float4*)(x + i);
        u16x4 o = { f2bf(v.x), f2bf(v.y), f2bf(v.z), f2bf(v.w) };
        *(u16x4*)(xb + i) = o;
        return;
    }
    const float* src; u16* dst; int C, bx, by;
    if (bid < 4096)      { src = Wq; dst = Wt;                          C = 2048; bx = bid & 63; by = bid >> 6; }
    else if (bid < 5120) { src = Wk; dst = Wt + (size_t)2048 * 2048;    C = 512;  int i = bid - 4096; bx = i & 15; by = i >> 4; }
    else if (bid < 6144) { src = Wv; dst = Wt + (size_t)2560 * 2048;    C = 512;  int i = bid - 5120; bx = i & 15; by = i >> 4; }
    else                 { src = Wo; dst = Wt + (size_t)3072 * 2048;    C = 2048; int i = bid - 6144; bx = i & 63; by = i >> 6; }
    __shared__ float tile[32][33];
    int c0 = bx * 32, r0 = by * 32;
    int tx = threadIdx.x, ty = threadIdx.y;   // (32, 8)
#pragma unroll
    for (int i = 0; i < 32; i += 8)
        tile[ty + i][tx] = src[(size_t)(r0 + ty + i) * C + c0 + tx];
    __syncthreads();
#pragma unroll
    for (int i = 0; i < 32; i += 8)
        dst[(size_t)(c0 + ty + i) * 2048 + r0 + tx] = f2bf(tile[tx][ty + i]);
}

// V columns of QKVb [4096][3072] (cols 2560..3071) -> VT [b][kv*128][2048]
__global__ void vtrans(const u16* __restrict__ QKV, u16* __restrict__ VT) {
    __shared__ u16 tile[32][33];
    int b = blockIdx.z;
    int c0 = blockIdx.x * 32, r0 = blockIdx.y * 32;
    int tx = threadIdx.x, ty = threadIdx.y;
#pragma unroll
    for (int i = 0; i < 32; i += 8)
        tile[ty + i][tx] = QKV[(size_t)(b * 2048 + r0 + ty + i) * 3072 + 2560 + c0 + tx];
    __syncthreads();
#pragma unroll
    for (int i = 0; i < 32; i += 8)
        VT[(size_t)(b * 512 + c0 + ty + i) * 2048 + r0 + tx] = tile[tx][ty + i];
}

// ---------------------------------------------------------------------------
// C[M][N] = A[M][K] @ Bt[N][K]^T, bf16 in, fp32 accum. XOR-swizzled LDS.
// ---------------------------------------------------------------------------
template <typename OT>
__global__ __launch_bounds__(256, 2) void gemm_bt(
    const u16* __restrict__ A, const u16* __restrict__ Bt,
    OT* __restrict__ C, int M, int N, int K)
{
    __shared__ u16 As[128 * 64];
    __shared__ u16 Bs[128 * 64];
    const int tid  = threadIdx.x;
    const int wave = tid >> 6, lane = tid & 63;
    const int quad = lane >> 4, l15 = lane & 15;
    const int bm0 = blockIdx.y * 128, bn0 = blockIdx.x * 128;
    const int wr = (wave >> 1) * 64, wc = (wave & 1) * 64;

    const f32x4 zero = {0.f, 0.f, 0.f, 0.f};
    f32x4 acc[4][4];
#pragma unroll
    for (int i = 0; i < 4; ++i)
#pragma unroll
        for (int j = 0; j < 4; ++j) acc[i][j] = zero;

    const int srow = lane >> 3;
    const int jsw  = ((lane & 7) ^ srow) * 8;

    for (int k0 = 0; k0 < K; k0 += 64) {
#pragma unroll
        for (int i = 0; i < 4; ++i) {
            int c = wave * 4 + i;
            gload16(A  + (size_t)(bm0 + c * 8 + srow) * K + k0 + jsw, As + c * 512);
            gload16(Bt + (size_t)(bn0 + c * 8 + srow) * K + k0 + jsw, Bs + c * 512);
        }
        __syncthreads();
#pragma unroll
        for (int ks = 0; ks < 2; ++ks) {
            bf16x8 a[4], b[4];
#pragma unroll
            for (int t = 0; t < 4; ++t) {
                int rd = ((ks * 4 + quad) ^ (l15 & 7)) * 8;
                a[t] = *(const bf16x8*)(As + (wr + t * 16 + l15) * 64 + rd);
                b[t] = *(const bf16x8*)(Bs + (wc + t * 16 + l15) * 64 + rd);
            }
#pragma unroll
            for (int i = 0; i < 4; ++i)
#pragma unroll
                for (int j = 0; j < 4; ++j)
                    acc[i][j] = __builtin_amdgcn_mfma_f32_16x16x32_bf16(a[i], b[j], acc[i][j], 0, 0, 0);
        }
        __syncthreads();
    }
#pragma unroll
    for (int i = 0; i < 4; ++i) {
        int grow = bm0 + wr + i * 16 + quad * 4;
#pragma unroll
        for (int j = 0; j < 4; ++j) {
            int gcol = bn0 + wc + j * 16 + l15;
#pragma unroll
            for (int r = 0; r < 4; ++r)
                store_c(&C[(size_t)(grow + r) * N + gcol], acc[i][j][r]);
        }
    }
}

// ---------------------------------------------------------------------------
// Flash attention, causal, GQA. 256 threads = 4 waves; waves 0-1 own q-tile A
// (32 rows each), waves 2-3 own q-tile B (pair (i, 31-i)). Each wave holds
// 2 m-subtiles of 16 rows -> every K/V fragment read feeds 2 MFMAs.
// K and V both double-buffered; ONE barrier per round (prefetch issued at
// round top, drained at bottom barrier under full compute cover).
// Fixed-max softmax (p = exp2(s*c1 - c2)); denominator via ones-MFMA.
// ---------------------------------------------------------------------------
__global__ __launch_bounds__(256, 2) void attn(
    const u16* __restrict__ QKV, const u16* __restrict__ VT, u16* __restrict__ Y)
{
    __shared__ u16 Ks[2][64 * 128];   // [key][d], chunk-swizzled  32KB
    __shared__ u16 Vs[2][128 * 64];   // [d][t],   chunk-swizzled  32KB
    __shared__ u16 Ps[4][16 * 80];    // per-wave P (16 rows, reused per mt) 10KB

    const int tid  = threadIdx.x;
    const int wave = tid >> 6, lane = tid & 63;
    const int quad = lane >> 4, l15 = lane & 15;
    const int pi = blockIdx.x;                 // 0..15
    const int qtA = pi, qtB = 31 - pi;
    const int bh = blockIdx.y;
    const int b = bh >> 4, h = bh & 15, kv = h >> 2;

    const int myqt = (wave < 2) ? qtA : qtB;
    const int qbase = (wave & 1) * 32;             // row base within the 64-row tile
    const int q0 = myqt * 64 + qbase;              // wave's first q row (32 rows)

    bf16x8 aq[2][4];
#pragma unroll
    for (int mt = 0; mt < 2; ++mt) {
        const u16* qp = QKV + (size_t)(b * 2048 + q0 + mt * 16 + l15) * 3072 + h * 128 + quad * 8;
#pragma unroll
        for (int ks = 0; ks < 4; ++ks) aq[mt][ks] = *(const bf16x8*)(qp + ks * 32);
    }

    bf16x8 ones;
#pragma unroll
    for (int i = 0; i < 8; ++i) ones[i] = __builtin_bit_cast(__bf16, (u16)0x3F80);

    const f32x4 zero = {0.f, 0.f, 0.f, 0.f};
    f32x4 o[2][8], o8[2];
#pragma unroll
    for (int mt = 0; mt < 2; ++mt) {
#pragma unroll
        for (int i = 0; i < 8; ++i) o[mt][i] = zero;
        o8[mt] = zero;
    }

    const u16* Kbase = QKV + 2048 + kv * 128;                      // + row*3072
    const u16* Vbase = VT + (size_t)((b * 4 + kv) * 128) * 2048;   // + d*2048
    u16* pw = &Ps[wave][0];

    const int kr = lane >> 4;
    const int vr = lane >> 3;
    const int vjs = ((lane & 7) ^ vr) * 8;

    // stage k-tile kt into buffer buf: 4 K-chunks + 4 V-chunks per wave
    auto stage = [&](int buf, int kt) {
#pragma unroll
        for (int i = 0; i < 4; ++i) {
            int ci = wave * 4 + i;
            int krow = ci * 4 + kr;
            int kjs = ((lane & 15) ^ (krow & 15)) * 8;
            gload16(Kbase + (size_t)(b * 2048 + kt * 64 + krow) * 3072 + kjs,
                    &Ks[buf][ci * 512]);
            int vrow = ci * 8 + vr;
            gload16(Vbase + (size_t)vrow * 2048 + kt * 64 + vjs, &Vs[buf][ci * 512]);
        }
    };

    const float c1 = 0.12752817f;    // (1/sqrt(128)) * log2(e)
    const float c2 = 28.85390082f;   // 20 * log2(e)

    stage(0, 0);
    __syncthreads();

    for (int kt = 0; kt <= qtB; ++kt) {
        const int cur = kt & 1;
        if (kt < qtB) stage(cur ^ 1, kt + 1);   // in flight across entire round's compute

        if (kt <= myqt) {
            const u16* Ksc = &Ks[cur][0];
            const u16* Vsc = &Vs[cur][0];

            // S = Q K^T: bk read once, feeds both m-subtiles
            f32x4 s[2][4];
#pragma unroll
            for (int mt = 0; mt < 2; ++mt)
#pragma unroll
                for (int i = 0; i < 4; ++i) s[mt][i] = zero;
#pragma unroll
            for (int ks = 0; ks < 4; ++ks)
#pragma unroll
                for (int kc = 0; kc < 4; ++kc) {
                    bf16x8 bk = *(const bf16x8*)(Ksc + (kc * 16 + l15) * 128 + (((ks * 4 + quad) ^ l15) * 8));
                    s[0][kc] = __builtin_amdgcn_mfma_f32_16x16x32_bf16(aq[0][ks], bk, s[0][kc], 0, 0, 0);
                    s[1][kc] = __builtin_amdgcn_mfma_f32_16x16x32_bf16(aq[1][ks], bk, s[1][kc], 0, 0, 0);
                }
            const bool diag = (kt == myqt);

#pragma unroll
            for (int mt = 0; mt < 2; ++mt) {
                // exp + P write (per-wave buffer, reused across mt; wave-local order)
#pragma unroll
                for (int kc = 0; kc < 4; ++kc)
#pragma unroll
                    for (int r = 0; r < 4; ++r) {
                        float arg = fmaf(s[mt][kc][r], c1, -c2);
                        if (diag && (kc * 16 + l15) > (qbase + mt * 16 + quad * 4 + r)) arg = -10000.f;
                        float p = __builtin_amdgcn_exp2f(arg);
                        pw[(quad * 4 + r) * 80 + kc * 16 + l15] = f2bf(p);
                    }
                asm volatile("" ::: "memory");
                // O[mt] += P V ; denominator via ones-column MFMA
#pragma unroll
                for (int ks2 = 0; ks2 < 2; ++ks2) {
                    bf16x8 pa = *(const bf16x8*)(pw + l15 * 80 + ks2 * 32 + quad * 8);
#pragma unroll
                    for (int d = 0; d < 8; ++d) {
                        bf16x8 bv = *(const bf16x8*)(Vsc + (d * 16 + l15) * 64 + (((ks2 * 4 + quad) ^ (l15 & 7)) * 8));
                        o[mt][d] = __builtin_amdgcn_mfma_f32_16x16x32_bf16(pa, bv, o[mt][d], 0, 0, 0);
                    }
                    o8[mt] = __builtin_amdgcn_mfma_f32_16x16x32_bf16(pa, ones, o8[mt], 0, 0, 0);
                }
                asm volatile("" ::: "memory");
            }
        }

        __syncthreads();   // drains this round's prefetch (covered by compute); protects buffers
    }

#pragma unroll
    for (int mt = 0; mt < 2; ++mt) {
        float inv[4];
#pragma unroll
        for (int r = 0; r < 4; ++r) inv[r] = 1.0f / o8[mt][r];
#pragma unroll
        for (int d = 0; d < 8; ++d)
#pragma unroll
            for (int r = 0; r < 4; ++r)
                Y[(size_t)(b * 2048 + q0 + mt * 16 + quad * 4 + r) * 2048 + h * 128 + d * 16 + l15] =
                    f2bf(o[mt][d][r] * inv[r]);
    }
}

// ---------------------------------------------------------------------------
extern "C" void kernel_launch(void* const* d_in, const int* in_sizes, int n_in,
                              void* d_out, int out_size, void* d_ws, size_t ws_size,
                              hipStream_t stream)
{
    const float* x  = (const float*)d_in[0];
    const float* Wq = (const float*)d_in[1];
    const float* Wk = (const float*)d_in[2];
    const float* Wv = (const float*)d_in[3];
    const float* Wo = (const float*)d_in[4];
    float* out = (float*)d_out;

    char* ws = (char*)d_ws;
    u16* xb   = (u16*)ws; ws += (size_t)4096 * 2048 * 2;  // 16MB; reused as Y
    u16* Wt   = (u16*)ws; ws += (size_t)5120 * 2048 * 2;  // 20MB (WqkvT + WoT)
    u16* QKVb = (u16*)ws; ws += (size_t)4096 * 3072 * 2;  // 24MB
    u16* VT   = (u16*)ws;                                 //  4MB; total 64MB
    u16* Y    = xb;   // xb dead after QKV GEMM
    u16* WoT  = Wt + (size_t)3072 * 2048;

    prep<<<18432, dim3(32, 8, 1), 0, stream>>>(x, Wq, Wk, Wv, Wo, xb, Wt);

    gemm_bt<u16><<<dim3(24, 32, 1), 256, 0, stream>>>(xb, Wt, QKVb, 4096, 3072, 2048);

    vtrans<<<dim3(16, 64, 2), dim3(32, 8, 1), 0, stream>>>(QKVb, VT);

    attn<<<dim3(16, 32, 1), 256, 0, stream>>>(QKVb, VT, Y);

    gemm_bt<float><<<dim3(16, 32, 1), 256, 0, stream>>>(Y, WoT, out, 4096, 2048, 2048);
}

// Round 7
// 273.523 us; speedup vs baseline: 1.0378x; 1.0378x over previous
//
#include <hip/hip_runtime.h>
#include <cstdint>

typedef unsigned short u16;
typedef unsigned int u32;
typedef __attribute__((ext_vector_type(8))) __bf16 bf16x8;
typedef __attribute__((ext_vector_type(4))) float f32x4;
typedef __attribute__((ext_vector_type(4))) unsigned short u16x4;

#define AS1 __attribute__((address_space(1)))
#define AS3 __attribute__((address_space(3)))

__device__ __forceinline__ void gload16(const void* g, void* l) {
    __builtin_amdgcn_global_load_lds((AS1 void*)g, (AS3 void*)l, 16, 0, 0);
}

// hardware bf16 convert (v_cvt_pk_bf16_f32), RNE
__device__ __forceinline__ u16 f2bf(float f) {
    return __builtin_bit_cast(u16, (__bf16)f);
}

__device__ __forceinline__ void store_c(u16* p, float v)   { *p = f2bf(v); }
__device__ __forceinline__ void store_c(float* p, float v) { *p = v; }

// ---------------------------------------------------------------------------
// Fused prep: x fp32->bf16 cast + all 4 weight transpose+converts (one launch).
// blocks [0,4096): Wq  [4096,5120): Wk  [5120,6144): Wv  [6144,10240): Wo
// blocks [10240,18432): x cast (4 elems/thread)
// ---------------------------------------------------------------------------
__global__ void prep(const float* __restrict__ x,
                     const float* __restrict__ Wq, const float* __restrict__ Wk,
                     const float* __restrict__ Wv, const float* __restrict__ Wo,
                     u16* __restrict__ xb, u16* __restrict__ Wt)
{
    const int bid = blockIdx.x;
    if (bid >= 10240) {   // x cast
        int tid = threadIdx.y * 32 + threadIdx.x;
        size_t i = ((size_t)(bid - 10240) * 256 + tid) * 4;
        float4 v = *(const float4*)(x + i);
        u16x4 o = { f2bf(v.x), f2bf(v.y), f2bf(v.z), f2bf(v.w) };
        *(u16x4*)(xb + i) = o;
        return;
    }
    const float* src; u16* dst; int C, bx, by;
    if (bid < 4096)      { src = Wq; dst = Wt;                          C = 2048; bx = bid & 63; by = bid >> 6; }
    else if (bid < 5120) { src = Wk; dst = Wt + (size_t)2048 * 2048;    C = 512;  int i = bid - 4096; bx = i & 15; by = i >> 4; }
    else if (bid < 6144) { src = Wv; dst = Wt + (size_t)2560 * 2048;    C = 512;  int i = bid - 5120; bx = i & 15; by = i >> 4; }
    else                 { src = Wo; dst = Wt + (size_t)3072 * 2048;    C = 2048; int i = bid - 6144; bx = i & 63; by = i >> 6; }
    __shared__ float tile[32][33];
    int c0 = bx * 32, r0 = by * 32;
    int tx = threadIdx.x, ty = threadIdx.y;   // (32, 8)
#pragma unroll
    for (int i = 0; i < 32; i += 8)
        tile[ty + i][tx] = src[(size_t)(r0 + ty + i) * C + c0 + tx];
    __syncthreads();
#pragma unroll
    for (int i = 0; i < 32; i += 8)
        dst[(size_t)(c0 + ty + i) * 2048 + r0 + tx] = f2bf(tile[tx][ty + i]);
}

// V columns of QKVb [4096][3072] (cols 2560..3071) -> VT [b][kv*128][2048]
__global__ void vtrans(const u16* __restrict__ QKV, u16* __restrict__ VT) {
    __shared__ u16 tile[32][33];
    int b = blockIdx.z;
    int c0 = blockIdx.x * 32, r0 = blockIdx.y * 32;
    int tx = threadIdx.x, ty = threadIdx.y;
#pragma unroll
    for (int i = 0; i < 32; i += 8)
        tile[ty + i][tx] = QKV[(size_t)(b * 2048 + r0 + ty + i) * 3072 + 2560 + c0 + tx];
    __syncthreads();
#pragma unroll
    for (int i = 0; i < 32; i += 8)
        VT[(size_t)(b * 512 + c0 + ty + i) * 2048 + r0 + tx] = tile[tx][ty + i];
}

// ---------------------------------------------------------------------------
// C[M][N] = A[M][K] @ Bt[N][K]^T, bf16 in, fp32 accum. XOR-swizzled LDS.
// ---------------------------------------------------------------------------
template <typename OT>
__global__ __launch_bounds__(256, 2) void gemm_bt(
    const u16* __restrict__ A, const u16* __restrict__ Bt,
    OT* __restrict__ C, int M, int N, int K)
{
    __shared__ u16 As[128 * 64];
    __shared__ u16 Bs[128 * 64];
    const int tid  = threadIdx.x;
    const int wave = tid >> 6, lane = tid & 63;
    const int quad = lane >> 4, l15 = lane & 15;
    const int bm0 = blockIdx.y * 128, bn0 = blockIdx.x * 128;
    const int wr = (wave >> 1) * 64, wc = (wave & 1) * 64;

    const f32x4 zero = {0.f, 0.f, 0.f, 0.f};
    f32x4 acc[4][4];
#pragma unroll
    for (int i = 0; i < 4; ++i)
#pragma unroll
        for (int j = 0; j < 4; ++j) acc[i][j] = zero;

    const int srow = lane >> 3;
    const int jsw  = ((lane & 7) ^ srow) * 8;

    for (int k0 = 0; k0 < K; k0 += 64) {
#pragma unroll
        for (int i = 0; i < 4; ++i) {
            int c = wave * 4 + i;
            gload16(A  + (size_t)(bm0 + c * 8 + srow) * K + k0 + jsw, As + c * 512);
            gload16(Bt + (size_t)(bn0 + c * 8 + srow) * K + k0 + jsw, Bs + c * 512);
        }
        __syncthreads();
#pragma unroll
        for (int ks = 0; ks < 2; ++ks) {
            bf16x8 a[4], b[4];
#pragma unroll
            for (int t = 0; t < 4; ++t) {
                int rd = ((ks * 4 + quad) ^ (l15 & 7)) * 8;
                a[t] = *(const bf16x8*)(As + (wr + t * 16 + l15) * 64 + rd);
                b[t] = *(const bf16x8*)(Bs + (wc + t * 16 + l15) * 64 + rd);
            }
#pragma unroll
            for (int i = 0; i < 4; ++i)
#pragma unroll
                for (int j = 0; j < 4; ++j)
                    acc[i][j] = __builtin_amdgcn_mfma_f32_16x16x32_bf16(a[i], b[j], acc[i][j], 0, 0, 0);
        }
        __syncthreads();
    }
#pragma unroll
    for (int i = 0; i < 4; ++i) {
        int grow = bm0 + wr + i * 16 + quad * 4;
#pragma unroll
        for (int j = 0; j < 4; ++j) {
            int gcol = bn0 + wc + j * 16 + l15;
#pragma unroll
            for (int r = 0; r < 4; ++r)
                store_c(&C[(size_t)(grow + r) * N + gcol], acc[i][j][r]);
        }
    }
}

// ---------------------------------------------------------------------------
// Flash attention, causal, GQA with HEAD-PAIR sharing: block = one 64-row
// q-tile x 2 heads of the same kv group. 4 waves x 16 rows; each wave computes
// both heads' subtiles -> every bk/bv LDS read feeds 2 MFMAs, zero predication
// waste (identical kt range). K+V double-buffered, ONE barrier per round.
// LPT dispatch: qt = 31 - blockIdx.y (big tiles first; backfill balances).
// Fixed-max softmax (p = exp2(s*c1 - c2)); denominator via ones-MFMA.
// ---------------------------------------------------------------------------
__global__ __launch_bounds__(256, 2) void attn(
    const u16* __restrict__ QKV, const u16* __restrict__ VT, u16* __restrict__ Y)
{
    __shared__ u16 Ks[2][64 * 128];     // [key][d], chunk-swizzled   32KB
    __shared__ u16 Vs[2][128 * 64];     // [d][t],   chunk-swizzled   32KB
    __shared__ u16 Ps[4][2][16 * 64];   // per-wave per-head P, LD=64 XOR 16KB

    const int tid  = threadIdx.x;
    const int wave = tid >> 6, lane = tid & 63;
    const int quad = lane >> 4, l15 = lane & 15;
    const int qt = 31 - (int)blockIdx.y;       // LPT: big tiles dispatch first
    const int hb = blockIdx.x;                 // 0..15
    const int b = hb >> 3, kv = (hb >> 1) & 3, hp = hb & 1;
    const int h0 = kv * 4 + hp * 2;            // heads h0, h0+1
    const int q0 = qt * 64 + wave * 16;        // wave's 16 q-rows (both heads)

    bf16x8 aq[2][4];
#pragma unroll
    for (int hh = 0; hh < 2; ++hh) {
        const u16* qp = QKV + (size_t)(b * 2048 + q0 + l15) * 3072 + (h0 + hh) * 128 + quad * 8;
#pragma unroll
        for (int ks = 0; ks < 4; ++ks) aq[hh][ks] = *(const bf16x8*)(qp + ks * 32);
    }

    bf16x8 ones;
#pragma unroll
    for (int i = 0; i < 8; ++i) ones[i] = __builtin_bit_cast(__bf16, (u16)0x3F80);

    const f32x4 zero = {0.f, 0.f, 0.f, 0.f};
    f32x4 o[2][8], o8[2];
#pragma unroll
    for (int hh = 0; hh < 2; ++hh) {
#pragma unroll
        for (int i = 0; i < 8; ++i) o[hh][i] = zero;
        o8[hh] = zero;
    }

    const u16* Kbase = QKV + 2048 + kv * 128;                      // + row*3072
    const u16* Vbase = VT + (size_t)((b * 4 + kv) * 128) * 2048;   // + d*2048

    const int kr = lane >> 4;
    const int vr = lane >> 3;
    const int vjs = ((lane & 7) ^ vr) * 8;

    // stage k-tile kt into buffer buf: 4 K-chunks + 4 V-chunks per wave
    auto stage = [&](int buf, int kt) {
#pragma unroll
        for (int i = 0; i < 4; ++i) {
            int ci = wave * 4 + i;
            int krow = ci * 4 + kr;
            int kjs = ((lane & 15) ^ (krow & 15)) * 8;
            gload16(Kbase + (size_t)(b * 2048 + kt * 64 + krow) * 3072 + kjs,
                    &Ks[buf][ci * 512]);
            int vrow = ci * 8 + vr;
            gload16(Vbase + (size_t)vrow * 2048 + kt * 64 + vjs, &Vs[buf][ci * 512]);
        }
    };

    const float c1 = 0.12752817f;    // (1/sqrt(128)) * log2(e)
    const float c2 = 28.85390082f;   // 20 * log2(e)

    stage(0, 0);
    __syncthreads();

    for (int kt = 0; kt <= qt; ++kt) {
        const int cur = kt & 1;
        if (kt < qt) stage(cur ^ 1, kt + 1);   // in flight across whole round

        const u16* Ksc = &Ks[cur][0];
        const u16* Vsc = &Vs[cur][0];

        // S = Q K^T: bk read once, feeds both heads
        f32x4 s[2][4];
#pragma unroll
        for (int hh = 0; hh < 2; ++hh)
#pragma unroll
            for (int i = 0; i < 4; ++i) s[hh][i] = zero;
#pragma unroll
        for (int ks = 0; ks < 4; ++ks)
#pragma unroll
            for (int kc = 0; kc < 4; ++kc) {
                bf16x8 bk = *(const bf16x8*)(Ksc + (kc * 16 + l15) * 128 + (((ks * 4 + quad) ^ l15) * 8));
                s[0][kc] = __builtin_amdgcn_mfma_f32_16x16x32_bf16(aq[0][ks], bk, s[0][kc], 0, 0, 0);
                s[1][kc] = __builtin_amdgcn_mfma_f32_16x16x32_bf16(aq[1][ks], bk, s[1][kc], 0, 0, 0);
            }
        const bool diag = (kt == qt);

        // exp + P write (per-head LDS buffer, XOR-chunk swizzle, LD=64)
#pragma unroll
        for (int hh = 0; hh < 2; ++hh) {
            u16* pw = &Ps[wave][hh][0];
#pragma unroll
            for (int kc = 0; kc < 4; ++kc)
#pragma unroll
                for (int r = 0; r < 4; ++r) {
                    float arg = fmaf(s[hh][kc][r], c1, -c2);
                    if (diag && (kc * 16 + l15) > (wave * 16 + quad * 4 + r)) arg = -10000.f;
                    float p = __builtin_amdgcn_exp2f(arg);
                    int row = quad * 4 + r;
                    int chunk = (kc * 2 + (l15 >> 3)) ^ (row & 7);
                    pw[row * 64 + chunk * 8 + (l15 & 7)] = f2bf(p);
                }
        }
        asm volatile("" ::: "memory");

        // O += P V: bv read once, feeds both heads; denom via ones-MFMA
#pragma unroll
        for (int ks2 = 0; ks2 < 2; ++ks2) {
            const int prd = ((ks2 * 4 + quad) ^ (l15 & 7)) * 8;
            bf16x8 pa0 = *(const bf16x8*)(&Ps[wave][0][0] + l15 * 64 + prd);
            bf16x8 pa1 = *(const bf16x8*)(&Ps[wave][1][0] + l15 * 64 + prd);
#pragma unroll
            for (int d = 0; d < 8; ++d) {
                bf16x8 bv = *(const bf16x8*)(Vsc + (d * 16 + l15) * 64 + prd);
                o[0][d] = __builtin_amdgcn_mfma_f32_16x16x32_bf16(pa0, bv, o[0][d], 0, 0, 0);
                o[1][d] = __builtin_amdgcn_mfma_f32_16x16x32_bf16(pa1, bv, o[1][d], 0, 0, 0);
            }
            o8[0] = __builtin_amdgcn_mfma_f32_16x16x32_bf16(pa0, ones, o8[0], 0, 0, 0);
            o8[1] = __builtin_amdgcn_mfma_f32_16x16x32_bf16(pa1, ones, o8[1], 0, 0, 0);
        }

        __syncthreads();   // drains this round's prefetch (covered by compute)
    }

#pragma unroll
    for (int hh = 0; hh < 2; ++hh) {
        float inv[4];
#pragma unroll
        for (int r = 0; r < 4; ++r) inv[r] = 1.0f / o8[hh][r];
#pragma unroll
        for (int d = 0; d < 8; ++d)
#pragma unroll
            for (int r = 0; r < 4; ++r)
                Y[(size_t)(b * 2048 + q0 + quad * 4 + r) * 2048 + (h0 + hh) * 128 + d * 16 + l15] =
                    f2bf(o[hh][d][r] * inv[r]);
    }
}

// ---------------------------------------------------------------------------
extern "C" void kernel_launch(void* const* d_in, const int* in_sizes, int n_in,
                              void* d_out, int out_size, void* d_ws, size_t ws_size,
                              hipStream_t stream)
{
    const float* x  = (const float*)d_in[0];
    const float* Wq = (const float*)d_in[1];
    const float* Wk = (const float*)d_in[2];
    const float* Wv = (const float*)d_in[3];
    const float* Wo = (const float*)d_in[4];
    float* out = (float*)d_out;

    char* ws = (char*)d_ws;
    u16* xb   = (u16*)ws; ws += (size_t)4096 * 2048 * 2;  // 16MB; reused as Y
    u16* Wt   = (u16*)ws; ws += (size_t)5120 * 2048 * 2;  // 20MB (WqkvT + WoT)
    u16* QKVb = (u16*)ws; ws += (size_t)4096 * 3072 * 2;  // 24MB
    u16* VT   = (u16*)ws;                                 //  4MB; total 64MB
    u16* Y    = xb;   // xb dead after QKV GEMM
    u16* WoT  = Wt + (size_t)3072 * 2048;

    prep<<<18432, dim3(32, 8, 1), 0, stream>>>(x, Wq, Wk, Wv, Wo, xb, Wt);

    gemm_bt<u16><<<dim3(24, 32, 1), 256, 0, stream>>>(xb, Wt, QKVb, 4096, 3072, 2048);

    vtrans<<<dim3(16, 64, 2), dim3(32, 8, 1), 0, stream>>>(QKVb, VT);

    attn<<<dim3(16, 32, 1), 256, 0, stream>>>(QKVb, VT, Y);

    gemm_bt<float><<<dim3(16, 32, 1), 256, 0, stream>>>(Y, WoT, out, 4096, 2048, 2048);
}